// Round 4
// baseline (604.285 us; speedup 1.0000x reference)
//
#include <hip/hip_runtime.h>

#define NTOT 262144
#define BN   32
#define NT   256
#define SXS  296     // sX row stride in shorts (288 + 8 pad -> conflict-free b128 reads)

typedef __attribute__((ext_vector_type(8))) short bf16x8;
typedef __attribute__((ext_vector_type(4))) float f32x4;

static __device__ __forceinline__ unsigned short f2b(float x) {
    union { float f; unsigned u; } c; c.f = x;
    unsigned r = c.u + 0x7FFFu + ((c.u >> 16) & 1u);   // RNE
    return (unsigned short)(r >> 16);
}

static __device__ __forceinline__ bf16x8 cvt8(const float* p) {
    float4 x = *(const float4*)p, y = *(const float4*)(p + 4);
    bf16x8 r;
    r[0] = (short)f2b(x.x); r[1] = (short)f2b(x.y); r[2] = (short)f2b(x.z); r[3] = (short)f2b(x.w);
    r[4] = (short)f2b(y.x); r[5] = (short)f2b(y.y); r[6] = (short)f2b(y.z); r[7] = (short)f2b(y.w);
    return r;
}

// Pack W_m_w [256][288] and W_g_w [32][256] to bf16, k-chunked:
//   wmw chunk ks: wp[ks*8192 + o*32 + kk]          (ks<9)
//   wgw chunk ks: wp[73728 + ks*1024 + o*32 + kk]  (ks<8)
// Each wave's B-fragment load covers a contiguous 1KB span -> coalesced, L1/L2-hit.
__global__ void pack_w(const float* __restrict__ Wmw, const float* __restrict__ Wgw,
                       unsigned short* __restrict__ wp) {
    int t = blockIdx.x * 256 + threadIdx.x;
    if (t < 73728) {
        int o = t / 288, k = t % 288;
        wp[(k >> 5) * 8192 + o * 32 + (k & 31)] = f2b(Wmw[t]);
    } else if (t < 81920) {
        int j = t - 73728;
        int o = j >> 8, k = j & 255;
        wp[73728 + (k >> 5) * 1024 + o * 32 + (k & 31)] = f2b(Wgw[j]);
    }
}

template<int USE_WS>
__global__ __launch_bounds__(NT, 4)
void gvp_main(const float* __restrict__ s, const float* __restrict__ V,
              const float* __restrict__ Wh, const float* __restrict__ Wmu,
              const float* __restrict__ Wmw, const float* __restrict__ Wmb,
              const float* __restrict__ Wgw, const float* __restrict__ Wgb,
              const unsigned short* __restrict__ wpack,
              float* __restrict__ out)
{
    // LDS 35,328 B -> 4 blocks/CU:
    //   sX    bf16 [32][296] 18944 B  (s|s_h -> sigmoid(s_m) -> relu f32 16-row passes -> V_dash f32)
    //   sV    f32  [32][96]  12288 B  (V tile, then V_h)
    //   sGate f32  [32][32]   4096 B
    __shared__ __attribute__((aligned(16))) unsigned short sX[BN * SXS];
    __shared__ __attribute__((aligned(16))) float sV[BN * 96];
    __shared__ __attribute__((aligned(16))) float sGate[BN * 32];

    const int t  = threadIdx.x;
    const int w  = t >> 6, l = t & 63;
    const int fr = l & 15, fq = l >> 4;
    const int n0 = blockIdx.x * BN;

    // ---------------- stage s -> sX (bf16), V -> sV ----------------
    #pragma unroll
    for (int i = 0; i < 8; ++i) {
        int n = i * 4 + w;
        float4 x4 = *(const float4*)&s[(size_t)(n0 + n) * 256 + 4 * l];
        ushort4 h4; h4.x = f2b(x4.x); h4.y = f2b(x4.y); h4.z = f2b(x4.z); h4.w = f2b(x4.w);
        *(ushort4*)&sX[n * SXS + 4 * l] = h4;
    }
    #pragma unroll
    for (int i = 0; i < 3; ++i) {
        int f = i * NT + t;
        *(float4*)&sV[f * 4] = *(const float4*)&V[(size_t)n0 * 96 + f * 4];
    }
    __syncthreads();

    // ---------------- phase A: V_h = Wh@V (f32), s_h -> sX cols 256.. ----------
    float vh[4][3];
    #pragma unroll
    for (int i = 0; i < 4; ++i) {
        int p = i * NT + t;
        int n = p >> 5, h = p & 31;
        const float4* vt4 = (const float4*)&sV[n * 96];
        const float4* wh4 = (const float4*)&Wh[h * 32];
        float a0 = 0.f, a1 = 0.f, a2 = 0.f;
        #pragma unroll
        for (int v4 = 0; v4 < 8; ++v4) {
            float4 wv = wh4[v4];
            float4 p0 = vt4[v4 * 3 + 0], p1 = vt4[v4 * 3 + 1], p2 = vt4[v4 * 3 + 2];
            a0 = fmaf(wv.x, p0.x, a0); a1 = fmaf(wv.x, p0.y, a1); a2 = fmaf(wv.x, p0.z, a2);
            a0 = fmaf(wv.y, p0.w, a0); a1 = fmaf(wv.y, p1.x, a1); a2 = fmaf(wv.y, p1.y, a2);
            a0 = fmaf(wv.z, p1.z, a0); a1 = fmaf(wv.z, p1.w, a1); a2 = fmaf(wv.z, p2.x, a2);
            a0 = fmaf(wv.w, p2.y, a0); a1 = fmaf(wv.w, p2.z, a1); a2 = fmaf(wv.w, p2.w, a2);
        }
        vh[i][0] = a0; vh[i][1] = a1; vh[i][2] = a2;
        float nrm = sqrtf(fmaf(a0, a0, fmaf(a1, a1, a2 * a2)));
        sX[n * SXS + 256 + h] = f2b(fmaxf(nrm, 1e-4f));
    }
    __syncthreads();            // V-tile reads done; s_h visible
    #pragma unroll
    for (int i = 0; i < 4; ++i) {
        int p = i * NT + t;
        int n = p >> 5, h = p & 31;
        sV[n * 96 + h * 3 + 0] = vh[i][0];
        sV[n * 96 + h * 3 + 1] = vh[i][1];
        sV[n * 96 + h * 3 + 2] = vh[i][2];
    }

    // ---------------- main GEMM: s_m = [s|s_h] @ Wmw^T (B direct from global) ----
    f32x4 acc[2][4];
    #pragma unroll
    for (int mt = 0; mt < 2; ++mt)
        #pragma unroll
        for (int j = 0; j < 4; ++j) acc[mt][j] = (f32x4){0.f, 0.f, 0.f, 0.f};

    #pragma unroll
    for (int ks = 0; ks < 9; ++ks) {
        bf16x8 a0 = *(const bf16x8*)&sX[fr * SXS + ks * 32 + fq * 8];
        bf16x8 a1 = *(const bf16x8*)&sX[(16 + fr) * SXS + ks * 32 + fq * 8];
        bf16x8 b[4];
        #pragma unroll
        for (int j = 0; j < 4; ++j) {
            int o = w * 64 + j * 16 + fr;
            if (USE_WS) b[j] = *(const bf16x8*)&wpack[ks * 8192 + o * 32 + fq * 8];
            else        b[j] = cvt8(&Wmw[o * 288 + ks * 32 + fq * 8]);
        }
        #pragma unroll
        for (int j = 0; j < 4; ++j) {
            acc[0][j] = __builtin_amdgcn_mfma_f32_16x16x32_bf16(a0, b[j], acc[0][j], 0, 0, 0);
            acc[1][j] = __builtin_amdgcn_mfma_f32_16x16x32_bf16(a1, b[j], acc[1][j], 0, 0, 0);
        }
    }

    // bias per thread (4 cols)
    float bias[4];
    #pragma unroll
    for (int j = 0; j < 4; ++j) bias[j] = Wmb[w * 64 + j * 16 + fr];
    __syncthreads();            // A-frag reads done -> sX writable

    // ---------------- sigmoid(s_m) -> sX bf16 (acc stays live in regs) ----------
    #pragma unroll
    for (int mt = 0; mt < 2; ++mt)
        #pragma unroll
        for (int j = 0; j < 4; ++j) {
            int col = w * 64 + j * 16 + fr;
            #pragma unroll
            for (int r = 0; r < 4; ++r) {
                int node = mt * 16 + fq * 4 + r;
                float m = acc[mt][j][r] + bias[j];
                sX[node * SXS + col] = f2b(1.f / (1.f + __expf(-m)));
            }
        }
    __syncthreads();

    // ---------------- gate GEMM: sigmoid(s_m) @ Wgw^T -> sigmoid -> sGate ------
    {
        const int gmt = w & 1, gnt = w >> 1;
        f32x4 g = (f32x4){0.f, 0.f, 0.f, 0.f};
        #pragma unroll
        for (int ks = 0; ks < 8; ++ks) {
            bf16x8 a = *(const bf16x8*)&sX[(gmt * 16 + fr) * SXS + ks * 32 + fq * 8];
            bf16x8 b;
            if (USE_WS) b = *(const bf16x8*)&wpack[73728 + ks * 1024 + (gnt * 16 + fr) * 32 + fq * 8];
            else        b = cvt8(&Wgw[(gnt * 16 + fr) * 256 + ks * 32 + fq * 8]);
            g = __builtin_amdgcn_mfma_f32_16x16x32_bf16(a, b, g, 0, 0, 0);
        }
        int mo = gnt * 16 + fr;
        float gb = Wgb[mo];
        #pragma unroll
        for (int r = 0; r < 4; ++r) {
            int node = gmt * 16 + fq * 4 + r;
            sGate[node * 32 + mo] = 1.f / (1.f + __expf(-(g[r] + gb)));
        }
    }
    __syncthreads();            // gate done; sX dead -> f32 relu restage region

    // ---------------- s_dash: relu restage through sX, full-line f4 stores -----
    float* sRel = (float*)sX;   // [16][260] f32 per pass (16640 B <= 18944 B)
    #pragma unroll
    for (int mt = 0; mt < 2; ++mt) {
        #pragma unroll
        for (int j = 0; j < 4; ++j) {
            int col = w * 64 + j * 16 + fr;
            #pragma unroll
            for (int r = 0; r < 4; ++r)
                sRel[(fq * 4 + r) * 260 + col] = fmaxf(acc[mt][j][r] + bias[j], 0.f);
        }
        __syncthreads();
        #pragma unroll
        for (int i = 0; i < 4; ++i) {
            int flat = i * NT + t;           // 0..1023 f4 slots (16 rows x 64)
            int row = flat >> 6, c4 = flat & 63;
            float4 v4 = *(const float4*)&sRel[row * 260 + c4 * 4];
            *(float4*)&out[(size_t)(n0 + mt * 16 + row) * 256 + c4 * 4] = v4;
        }
        __syncthreads();
    }

    // ---------------- phase D: V_mu = Wmu@V_h (f32); gate; coalesced store -----
    float* sc = (float*)sX;     // f32 V_dash scratch [32][96]
    #pragma unroll
    for (int i = 0; i < 4; ++i) {
        int p = i * NT + t;
        int n = p >> 5, m = p & 31;
        const float4* vt4 = (const float4*)&sV[n * 96];
        const float4* wm4 = (const float4*)&Wmu[m * 32];
        float a0 = 0.f, a1 = 0.f, a2 = 0.f;
        #pragma unroll
        for (int v4 = 0; v4 < 8; ++v4) {
            float4 wv = wm4[v4];
            float4 p0 = vt4[v4 * 3 + 0], p1 = vt4[v4 * 3 + 1], p2 = vt4[v4 * 3 + 2];
            a0 = fmaf(wv.x, p0.x, a0); a1 = fmaf(wv.x, p0.y, a1); a2 = fmaf(wv.x, p0.z, a2);
            a0 = fmaf(wv.y, p0.w, a0); a1 = fmaf(wv.y, p1.x, a1); a2 = fmaf(wv.y, p1.y, a2);
            a0 = fmaf(wv.z, p1.z, a0); a1 = fmaf(wv.z, p1.w, a1); a2 = fmaf(wv.z, p2.x, a2);
            a0 = fmaf(wv.w, p2.y, a0); a1 = fmaf(wv.w, p2.z, a1); a2 = fmaf(wv.w, p2.w, a2);
        }
        float g = sGate[n * 32 + m];
        sc[n * 96 + m * 3 + 0] = g * a0;
        sc[n * 96 + m * 3 + 1] = g * a1;
        sc[n * 96 + m * 3 + 2] = g * a2;
    }
    __syncthreads();
    const size_t VBASE = (size_t)NTOT * 256;
    #pragma unroll
    for (int i = 0; i < 3; ++i) {
        int f = i * NT + t;
        *(float4*)&out[VBASE + (size_t)n0 * 96 + f * 4] = *(const float4*)&sc[f * 4];
    }
}

extern "C" void kernel_launch(void* const* d_in, const int* in_sizes, int n_in,
                              void* d_out, int out_size, void* d_ws, size_t ws_size,
                              hipStream_t stream) {
    const float* s   = (const float*)d_in[0];
    const float* V   = (const float*)d_in[1];
    const float* Wh  = (const float*)d_in[2];
    const float* Wmu = (const float*)d_in[3];
    const float* Wmw = (const float*)d_in[4];
    const float* Wmb = (const float*)d_in[5];
    const float* Wgw = (const float*)d_in[6];
    const float* Wgb = (const float*)d_in[7];
    float* out = (float*)d_out;

    dim3 grid(NTOT / BN);   // 8192
    dim3 block(NT);         // 256

    if (ws_size >= 163840) {
        pack_w<<<320, 256, 0, stream>>>(Wmw, Wgw, (unsigned short*)d_ws);
        gvp_main<1><<<grid, block, 0, stream>>>(s, V, Wh, Wmu, Wmw, Wmb, Wgw, Wgb,
                                                (const unsigned short*)d_ws, out);
    } else {
        gvp_main<0><<<grid, block, 0, stream>>>(s, V, Wh, Wmu, Wmw, Wmb, Wgw, Wgb,
                                                nullptr, out);
    }
}

// Round 5
// 602.446 us; speedup vs baseline: 1.0031x; 1.0031x over previous
//
#include <hip/hip_runtime.h>

#define NTOT 262144
#define BN   32
#define NT   256
#define SXS  296     // sX row stride in shorts (288 + 8 pad -> conflict-free b128 reads)

typedef __attribute__((ext_vector_type(8))) short bf16x8;
typedef __attribute__((ext_vector_type(4))) float f32x4;

static __device__ __forceinline__ unsigned short f2b(float x) {
    union { float f; unsigned u; } c; c.f = x;
    unsigned r = c.u + 0x7FFFu + ((c.u >> 16) & 1u);   // RNE
    return (unsigned short)(r >> 16);
}

static __device__ __forceinline__ bf16x8 cvt8(const float* p) {
    float4 x = *(const float4*)p, y = *(const float4*)(p + 4);
    bf16x8 r;
    r[0] = (short)f2b(x.x); r[1] = (short)f2b(x.y); r[2] = (short)f2b(x.z); r[3] = (short)f2b(x.w);
    r[4] = (short)f2b(y.x); r[5] = (short)f2b(y.y); r[6] = (short)f2b(y.z); r[7] = (short)f2b(y.w);
    return r;
}

// Pack W_m_w [256][288] and W_g_w [32][256] to bf16, k-chunked:
//   wmw chunk ks: wp[ks*8192 + o*32 + kk]          (ks<9)
//   wgw chunk ks: wp[73728 + ks*1024 + o*32 + kk]  (ks<8)
// Each wave's B-fragment load covers a contiguous 1KB span -> coalesced, L2-hot.
__global__ void pack_w(const float* __restrict__ Wmw, const float* __restrict__ Wgw,
                       unsigned short* __restrict__ wp) {
    int t = blockIdx.x * 256 + threadIdx.x;
    if (t < 73728) {
        int o = t / 288, k = t % 288;
        wp[(k >> 5) * 8192 + o * 32 + (k & 31)] = f2b(Wmw[t]);
    } else if (t < 81920) {
        int j = t - 73728;
        int o = j >> 8, k = j & 255;
        wp[73728 + (k >> 5) * 1024 + o * 32 + (k & 31)] = f2b(Wgw[j]);
    }
}

template<int USE_WS>
__global__ __launch_bounds__(NT, 4)
void gvp_main(const float* __restrict__ s, const float* __restrict__ V,
              const float* __restrict__ Wh, const float* __restrict__ Wmu,
              const float* __restrict__ Wmw, const float* __restrict__ Wmb,
              const float* __restrict__ Wgw, const float* __restrict__ Wgb,
              const unsigned short* __restrict__ wpack,
              float* __restrict__ out)
{
    // LDS 35,328 B -> 4 blocks/CU (16 waves):
    //   sX    bf16 [32][296] 18944 B  (s|s_h -> sigmoid(s_m) -> f32 V_dash scratch)
    //   sV    f32  [32][96]  12288 B  (V tile, then V_h)
    //   sGate f32  [32][32]   4096 B
    __shared__ __attribute__((aligned(16))) unsigned short sX[BN * SXS];
    __shared__ __attribute__((aligned(16))) float sV[BN * 96];
    __shared__ __attribute__((aligned(16))) float sGate[BN * 32];

    const int t  = threadIdx.x;
    const int w  = t >> 6, l = t & 63;
    const int fr = l & 15, fq = l >> 4;
    const int n0 = blockIdx.x * BN;

    // ---------------- stage s -> sX (bf16), V -> sV ----------------
    #pragma unroll
    for (int i = 0; i < 8; ++i) {
        int n = i * 4 + w;
        float4 x4 = *(const float4*)&s[(size_t)(n0 + n) * 256 + 4 * l];
        ushort4 h4; h4.x = f2b(x4.x); h4.y = f2b(x4.y); h4.z = f2b(x4.z); h4.w = f2b(x4.w);
        *(ushort4*)&sX[n * SXS + 4 * l] = h4;
    }
    #pragma unroll
    for (int i = 0; i < 3; ++i) {
        int f = i * NT + t;
        *(float4*)&sV[f * 4] = *(const float4*)&V[(size_t)n0 * 96 + f * 4];
    }
    __syncthreads();

    // ---------------- phase A: V_h = Wh@V (f32), s_h -> sX cols 256.. ----------
    float vh[4][3];
    #pragma unroll
    for (int i = 0; i < 4; ++i) {
        int p = i * NT + t;
        int n = p >> 5, h = p & 31;
        const float4* vt4 = (const float4*)&sV[n * 96];
        const float4* wh4 = (const float4*)&Wh[h * 32];
        float a0 = 0.f, a1 = 0.f, a2 = 0.f;
        #pragma unroll
        for (int v4 = 0; v4 < 8; ++v4) {
            float4 wv = wh4[v4];
            float4 p0 = vt4[v4 * 3 + 0], p1 = vt4[v4 * 3 + 1], p2 = vt4[v4 * 3 + 2];
            a0 = fmaf(wv.x, p0.x, a0); a1 = fmaf(wv.x, p0.y, a1); a2 = fmaf(wv.x, p0.z, a2);
            a0 = fmaf(wv.y, p0.w, a0); a1 = fmaf(wv.y, p1.x, a1); a2 = fmaf(wv.y, p1.y, a2);
            a0 = fmaf(wv.z, p1.z, a0); a1 = fmaf(wv.z, p1.w, a1); a2 = fmaf(wv.z, p2.x, a2);
            a0 = fmaf(wv.w, p2.y, a0); a1 = fmaf(wv.w, p2.z, a1); a2 = fmaf(wv.w, p2.w, a2);
        }
        vh[i][0] = a0; vh[i][1] = a1; vh[i][2] = a2;
        float nrm = sqrtf(fmaf(a0, a0, fmaf(a1, a1, a2 * a2)));
        sX[n * SXS + 256 + h] = f2b(fmaxf(nrm, 1e-4f));
    }
    __syncthreads();            // all sV(V-tile) reads + s_h writes complete
    #pragma unroll
    for (int i = 0; i < 4; ++i) {
        int p = i * NT + t;
        int n = p >> 5, h = p & 31;
        sV[n * 96 + h * 3 + 0] = vh[i][0];
        sV[n * 96 + h * 3 + 1] = vh[i][1];
        sV[n * 96 + h * 3 + 2] = vh[i][2];
    }

    // ---------------- main GEMM: s_m = [s|s_h] @ Wmw^T ----------------
    // B-frags direct from packed global (L2-hot). unroll(1) + 1-deep prefetch
    // keeps live set ~95 VGPR -> no scratch spill (the round-3/4 regression).
    f32x4 acc[2][4];
    #pragma unroll
    for (int mt = 0; mt < 2; ++mt)
        #pragma unroll
        for (int j = 0; j < 4; ++j) acc[mt][j] = (f32x4){0.f, 0.f, 0.f, 0.f};

    bf16x8 bp0, bp1, bp2, bp3;
    {   // preload ks=0
        if (USE_WS) {
            const unsigned short* base = wpack + (w * 64 + fr) * 32 + fq * 8;
            bp0 = *(const bf16x8*)(base + 0 * 512);
            bp1 = *(const bf16x8*)(base + 1 * 512);
            bp2 = *(const bf16x8*)(base + 2 * 512);
            bp3 = *(const bf16x8*)(base + 3 * 512);
        } else {
            const float* base = Wmw + (w * 64 + fr) * 288 + fq * 8;
            bp0 = cvt8(base + 0 * 16 * 288);
            bp1 = cvt8(base + 1 * 16 * 288);
            bp2 = cvt8(base + 2 * 16 * 288);
            bp3 = cvt8(base + 3 * 16 * 288);
        }
    }
    #pragma unroll 1
    for (int ks = 0; ks < 9; ++ks) {
        bf16x8 b0 = bp0, b1 = bp1, b2 = bp2, b3 = bp3;
        if (ks < 8) {           // prefetch next chunk's B-frags
            if (USE_WS) {
                const unsigned short* base = wpack + (ks + 1) * 8192 + (w * 64 + fr) * 32 + fq * 8;
                bp0 = *(const bf16x8*)(base + 0 * 512);
                bp1 = *(const bf16x8*)(base + 1 * 512);
                bp2 = *(const bf16x8*)(base + 2 * 512);
                bp3 = *(const bf16x8*)(base + 3 * 512);
            } else {
                const float* base = Wmw + (w * 64 + fr) * 288 + (ks + 1) * 32 + fq * 8;
                bp0 = cvt8(base + 0 * 16 * 288);
                bp1 = cvt8(base + 1 * 16 * 288);
                bp2 = cvt8(base + 2 * 16 * 288);
                bp3 = cvt8(base + 3 * 16 * 288);
            }
        }
        bf16x8 a0 = *(const bf16x8*)&sX[fr * SXS + ks * 32 + fq * 8];
        bf16x8 a1 = *(const bf16x8*)&sX[(16 + fr) * SXS + ks * 32 + fq * 8];
        acc[0][0] = __builtin_amdgcn_mfma_f32_16x16x32_bf16(a0, b0, acc[0][0], 0, 0, 0);
        acc[1][0] = __builtin_amdgcn_mfma_f32_16x16x32_bf16(a1, b0, acc[1][0], 0, 0, 0);
        acc[0][1] = __builtin_amdgcn_mfma_f32_16x16x32_bf16(a0, b1, acc[0][1], 0, 0, 0);
        acc[1][1] = __builtin_amdgcn_mfma_f32_16x16x32_bf16(a1, b1, acc[1][1], 0, 0, 0);
        acc[0][2] = __builtin_amdgcn_mfma_f32_16x16x32_bf16(a0, b2, acc[0][2], 0, 0, 0);
        acc[1][2] = __builtin_amdgcn_mfma_f32_16x16x32_bf16(a1, b2, acc[1][2], 0, 0, 0);
        acc[0][3] = __builtin_amdgcn_mfma_f32_16x16x32_bf16(a0, b3, acc[0][3], 0, 0, 0);
        acc[1][3] = __builtin_amdgcn_mfma_f32_16x16x32_bf16(a1, b3, acc[1][3], 0, 0, 0);
    }

    float bias[4];
    #pragma unroll
    for (int j = 0; j < 4; ++j) bias[j] = Wmb[w * 64 + j * 16 + fr];
    __syncthreads();            // A-frag reads done -> sX writable

    // ---------------- epilogue: relu -> out (direct), sigmoid -> sX; acc dies --
    #pragma unroll
    for (int mt = 0; mt < 2; ++mt)
        #pragma unroll
        for (int j = 0; j < 4; ++j) {
            int col = w * 64 + j * 16 + fr;
            #pragma unroll
            for (int r = 0; r < 4; ++r) {
                int node = mt * 16 + fq * 4 + r;
                float m = acc[mt][j][r] + bias[j];
                out[(size_t)(n0 + node) * 256 + col] = fmaxf(m, 0.f);
                sX[node * SXS + col] = f2b(1.f / (1.f + __expf(-m)));
            }
        }
    __syncthreads();

    // ---------------- gate GEMM: sigmoid(s_m) @ Wgw^T -> sigmoid -> sGate ------
    {
        const int gmt = w & 1, gnt = w >> 1;
        f32x4 g = (f32x4){0.f, 0.f, 0.f, 0.f};
        #pragma unroll
        for (int ks = 0; ks < 8; ++ks) {
            bf16x8 a = *(const bf16x8*)&sX[(gmt * 16 + fr) * SXS + ks * 32 + fq * 8];
            bf16x8 b;
            if (USE_WS) b = *(const bf16x8*)&wpack[73728 + ks * 1024 + (gnt * 16 + fr) * 32 + fq * 8];
            else        b = cvt8(&Wgw[(gnt * 16 + fr) * 256 + ks * 32 + fq * 8]);
            g = __builtin_amdgcn_mfma_f32_16x16x32_bf16(a, b, g, 0, 0, 0);
        }
        int mo = gnt * 16 + fr;
        float gb = Wgb[mo];
        #pragma unroll
        for (int r = 0; r < 4; ++r) {
            int node = gmt * 16 + fq * 4 + r;
            sGate[node * 32 + mo] = 1.f / (1.f + __expf(-(g[r] + gb)));
        }
    }
    __syncthreads();            // gate ready; sX dead -> f32 V_dash scratch

    // ---------------- phase D: V_mu = Wmu@V_h (f32); gate; coalesced store -----
    float* sc = (float*)sX;
    #pragma unroll
    for (int i = 0; i < 4; ++i) {
        int p = i * NT + t;
        int n = p >> 5, m = p & 31;
        const float4* vt4 = (const float4*)&sV[n * 96];
        const float4* wm4 = (const float4*)&Wmu[m * 32];
        float a0 = 0.f, a1 = 0.f, a2 = 0.f;
        #pragma unroll
        for (int v4 = 0; v4 < 8; ++v4) {
            float4 wv = wm4[v4];
            float4 p0 = vt4[v4 * 3 + 0], p1 = vt4[v4 * 3 + 1], p2 = vt4[v4 * 3 + 2];
            a0 = fmaf(wv.x, p0.x, a0); a1 = fmaf(wv.x, p0.y, a1); a2 = fmaf(wv.x, p0.z, a2);
            a0 = fmaf(wv.y, p0.w, a0); a1 = fmaf(wv.y, p1.x, a1); a2 = fmaf(wv.y, p1.y, a2);
            a0 = fmaf(wv.z, p1.z, a0); a1 = fmaf(wv.z, p1.w, a1); a2 = fmaf(wv.z, p2.x, a2);
            a0 = fmaf(wv.w, p2.y, a0); a1 = fmaf(wv.w, p2.z, a1); a2 = fmaf(wv.w, p2.w, a2);
        }
        float g = sGate[n * 32 + m];
        sc[n * 96 + m * 3 + 0] = g * a0;
        sc[n * 96 + m * 3 + 1] = g * a1;
        sc[n * 96 + m * 3 + 2] = g * a2;
    }
    __syncthreads();
    const size_t VBASE = (size_t)NTOT * 256;
    #pragma unroll
    for (int i = 0; i < 3; ++i) {
        int f = i * NT + t;
        *(float4*)&out[VBASE + (size_t)n0 * 96 + f * 4] = *(const float4*)&sc[f * 4];
    }
}

extern "C" void kernel_launch(void* const* d_in, const int* in_sizes, int n_in,
                              void* d_out, int out_size, void* d_ws, size_t ws_size,
                              hipStream_t stream) {
    const float* s   = (const float*)d_in[0];
    const float* V   = (const float*)d_in[1];
    const float* Wh  = (const float*)d_in[2];
    const float* Wmu = (const float*)d_in[3];
    const float* Wmw = (const float*)d_in[4];
    const float* Wmb = (const float*)d_in[5];
    const float* Wgw = (const float*)d_in[6];
    const float* Wgb = (const float*)d_in[7];
    float* out = (float*)d_out;

    dim3 grid(NTOT / BN);   // 8192
    dim3 block(NT);         // 256

    if (ws_size >= 163840) {
        pack_w<<<320, 256, 0, stream>>>(Wmw, Wgw, (unsigned short*)d_ws);
        gvp_main<1><<<grid, block, 0, stream>>>(s, V, Wh, Wmu, Wmw, Wmb, Wgw, Wgb,
                                                (const unsigned short*)d_ws, out);
    } else {
        gvp_main<0><<<grid, block, 0, stream>>>(s, V, Wh, Wmu, Wmw, Wmb, Wgw, Wgb,
                                                nullptr, out);
    }
}

// Round 6
// 535.722 us; speedup vs baseline: 1.1280x; 1.1245x over previous
//
#include <hip/hip_runtime.h>

#define NTOT 262144
#define BN   32
#define NT   256
#define SXS  296     // sX row stride in shorts (288 + 8 pad -> conflict-free b128 reads)

typedef __attribute__((ext_vector_type(8))) short bf16x8;
typedef __attribute__((ext_vector_type(4))) float f32x4;

static __device__ __forceinline__ unsigned short f2b(float x) {
    union { float f; unsigned u; } c; c.f = x;
    unsigned r = c.u + 0x7FFFu + ((c.u >> 16) & 1u);   // RNE
    return (unsigned short)(r >> 16);
}

static __device__ __forceinline__ bf16x8 cvt8(const float* p) {
    float4 x = *(const float4*)p, y = *(const float4*)(p + 4);
    bf16x8 r;
    r[0] = (short)f2b(x.x); r[1] = (short)f2b(x.y); r[2] = (short)f2b(x.z); r[3] = (short)f2b(x.w);
    r[4] = (short)f2b(y.x); r[5] = (short)f2b(y.y); r[6] = (short)f2b(y.z); r[7] = (short)f2b(y.w);
    return r;
}

// Pack W_m_w [256][288] and W_g_w [32][256] to bf16, k-chunked:
//   wmw chunk ks: wp[ks*8192 + o*32 + kk]          (ks<9)
//   wgw chunk ks: wp[73728 + ks*1024 + o*32 + kk]  (ks<8)
// Each wave's B-fragment load covers a contiguous 1KB span -> coalesced, L2-hot.
__global__ void pack_w(const float* __restrict__ Wmw, const float* __restrict__ Wgw,
                       unsigned short* __restrict__ wp) {
    int t = blockIdx.x * 256 + threadIdx.x;
    if (t < 73728) {
        int o = t / 288, k = t % 288;
        wp[(k >> 5) * 8192 + o * 32 + (k & 31)] = f2b(Wmw[t]);
    } else if (t < 81920) {
        int j = t - 73728;
        int o = j >> 8, k = j & 255;
        wp[73728 + (k >> 5) * 1024 + o * 32 + (k & 31)] = f2b(Wgw[j]);
    }
}

// launch_bounds(NT,2): VGPR cap 256. (NT,4) made the backend target 64 VGPRs and
// spill the K-loop live set (acc 32 + prefetch 16 + A 8 + addr) to scratch ->
// ~600 MB/dispatch of HBM spill traffic (rounds 3-5 regression). LDS 35,328 B
// still yields 4 blocks/CU as long as the allocator lands <= 128 VGPRs.
template<int USE_WS>
__global__ __launch_bounds__(NT, 2)
void gvp_main(const float* __restrict__ s, const float* __restrict__ V,
              const float* __restrict__ Wh, const float* __restrict__ Wmu,
              const float* __restrict__ Wmw, const float* __restrict__ Wmb,
              const float* __restrict__ Wgw, const float* __restrict__ Wgb,
              const unsigned short* __restrict__ wpack,
              float* __restrict__ out)
{
    // LDS 35,328 B:
    //   sX    bf16 [32][296] 18944 B  (s|s_h -> sigmoid(s_m) -> f32 V_dash scratch)
    //   sV    f32  [32][96]  12288 B  (V tile, then V_h)
    //   sGate f32  [32][32]   4096 B
    __shared__ __attribute__((aligned(16))) unsigned short sX[BN * SXS];
    __shared__ __attribute__((aligned(16))) float sV[BN * 96];
    __shared__ __attribute__((aligned(16))) float sGate[BN * 32];

    const int t  = threadIdx.x;
    const int w  = t >> 6, l = t & 63;
    const int fr = l & 15, fq = l >> 4;
    const int n0 = blockIdx.x * BN;

    // ---------------- stage s -> sX (bf16), V -> sV ----------------
    #pragma unroll
    for (int i = 0; i < 8; ++i) {
        int n = i * 4 + w;
        float4 x4 = *(const float4*)&s[(size_t)(n0 + n) * 256 + 4 * l];
        ushort4 h4; h4.x = f2b(x4.x); h4.y = f2b(x4.y); h4.z = f2b(x4.z); h4.w = f2b(x4.w);
        *(ushort4*)&sX[n * SXS + 4 * l] = h4;
    }
    #pragma unroll
    for (int i = 0; i < 3; ++i) {
        int f = i * NT + t;
        *(float4*)&sV[f * 4] = *(const float4*)&V[(size_t)n0 * 96 + f * 4];
    }
    __syncthreads();

    // ---------------- phase A: V_h = Wh@V (f32), s_h -> sX cols 256.. ----------
    float vh[4][3];
    #pragma unroll
    for (int i = 0; i < 4; ++i) {
        int p = i * NT + t;
        int n = p >> 5, h = p & 31;
        const float4* vt4 = (const float4*)&sV[n * 96];
        const float4* wh4 = (const float4*)&Wh[h * 32];
        float a0 = 0.f, a1 = 0.f, a2 = 0.f;
        #pragma unroll
        for (int v4 = 0; v4 < 8; ++v4) {
            float4 wv = wh4[v4];
            float4 p0 = vt4[v4 * 3 + 0], p1 = vt4[v4 * 3 + 1], p2 = vt4[v4 * 3 + 2];
            a0 = fmaf(wv.x, p0.x, a0); a1 = fmaf(wv.x, p0.y, a1); a2 = fmaf(wv.x, p0.z, a2);
            a0 = fmaf(wv.y, p0.w, a0); a1 = fmaf(wv.y, p1.x, a1); a2 = fmaf(wv.y, p1.y, a2);
            a0 = fmaf(wv.z, p1.z, a0); a1 = fmaf(wv.z, p1.w, a1); a2 = fmaf(wv.z, p2.x, a2);
            a0 = fmaf(wv.w, p2.y, a0); a1 = fmaf(wv.w, p2.z, a1); a2 = fmaf(wv.w, p2.w, a2);
        }
        vh[i][0] = a0; vh[i][1] = a1; vh[i][2] = a2;
        float nrm = sqrtf(fmaf(a0, a0, fmaf(a1, a1, a2 * a2)));
        sX[n * SXS + 256 + h] = f2b(fmaxf(nrm, 1e-4f));
    }
    __syncthreads();            // all sV(V-tile) reads + s_h writes complete
    #pragma unroll
    for (int i = 0; i < 4; ++i) {
        int p = i * NT + t;
        int n = p >> 5, h = p & 31;
        sV[n * 96 + h * 3 + 0] = vh[i][0];
        sV[n * 96 + h * 3 + 1] = vh[i][1];
        sV[n * 96 + h * 3 + 2] = vh[i][2];
    }

    // ---------------- main GEMM: s_m = [s|s_h] @ Wmw^T ----------------
    // B-frags direct from packed global (L2-hot); 1-deep prefetch; no barriers.
    f32x4 acc[2][4];
    #pragma unroll
    for (int mt = 0; mt < 2; ++mt)
        #pragma unroll
        for (int j = 0; j < 4; ++j) acc[mt][j] = (f32x4){0.f, 0.f, 0.f, 0.f};

    bf16x8 bp0, bp1, bp2, bp3;
    {   // preload ks=0
        if (USE_WS) {
            const unsigned short* base = wpack + (w * 64 + fr) * 32 + fq * 8;
            bp0 = *(const bf16x8*)(base + 0 * 512);
            bp1 = *(const bf16x8*)(base + 1 * 512);
            bp2 = *(const bf16x8*)(base + 2 * 512);
            bp3 = *(const bf16x8*)(base + 3 * 512);
        } else {
            const float* base = Wmw + (w * 64 + fr) * 288 + fq * 8;
            bp0 = cvt8(base + 0 * 16 * 288);
            bp1 = cvt8(base + 1 * 16 * 288);
            bp2 = cvt8(base + 2 * 16 * 288);
            bp3 = cvt8(base + 3 * 16 * 288);
        }
    }
    #pragma unroll 1
    for (int ks = 0; ks < 9; ++ks) {
        bf16x8 b0 = bp0, b1 = bp1, b2 = bp2, b3 = bp3;
        if (ks < 8) {           // prefetch next chunk's B-frags
            if (USE_WS) {
                const unsigned short* base = wpack + (ks + 1) * 8192 + (w * 64 + fr) * 32 + fq * 8;
                bp0 = *(const bf16x8*)(base + 0 * 512);
                bp1 = *(const bf16x8*)(base + 1 * 512);
                bp2 = *(const bf16x8*)(base + 2 * 512);
                bp3 = *(const bf16x8*)(base + 3 * 512);
            } else {
                const float* base = Wmw + (w * 64 + fr) * 288 + (ks + 1) * 32 + fq * 8;
                bp0 = cvt8(base + 0 * 16 * 288);
                bp1 = cvt8(base + 1 * 16 * 288);
                bp2 = cvt8(base + 2 * 16 * 288);
                bp3 = cvt8(base + 3 * 16 * 288);
            }
        }
        bf16x8 a0 = *(const bf16x8*)&sX[fr * SXS + ks * 32 + fq * 8];
        bf16x8 a1 = *(const bf16x8*)&sX[(16 + fr) * SXS + ks * 32 + fq * 8];
        acc[0][0] = __builtin_amdgcn_mfma_f32_16x16x32_bf16(a0, b0, acc[0][0], 0, 0, 0);
        acc[1][0] = __builtin_amdgcn_mfma_f32_16x16x32_bf16(a1, b0, acc[1][0], 0, 0, 0);
        acc[0][1] = __builtin_amdgcn_mfma_f32_16x16x32_bf16(a0, b1, acc[0][1], 0, 0, 0);
        acc[1][1] = __builtin_amdgcn_mfma_f32_16x16x32_bf16(a1, b1, acc[1][1], 0, 0, 0);
        acc[0][2] = __builtin_amdgcn_mfma_f32_16x16x32_bf16(a0, b2, acc[0][2], 0, 0, 0);
        acc[1][2] = __builtin_amdgcn_mfma_f32_16x16x32_bf16(a1, b2, acc[1][2], 0, 0, 0);
        acc[0][3] = __builtin_amdgcn_mfma_f32_16x16x32_bf16(a0, b3, acc[0][3], 0, 0, 0);
        acc[1][3] = __builtin_amdgcn_mfma_f32_16x16x32_bf16(a1, b3, acc[1][3], 0, 0, 0);
    }

    float bias[4];
    #pragma unroll
    for (int j = 0; j < 4; ++j) bias[j] = Wmb[w * 64 + j * 16 + fr];
    __syncthreads();            // A-frag reads done -> sX writable

    // ---------------- epilogue: relu -> out, sigmoid -> sX; j INNERMOST --------
    // j-inner: 4 consecutive stores cover a contiguous, line-aligned 256 B span
    // per row (cols w*64..w*64+63) -> full 128 B lines complete within 4 instrs.
    #pragma unroll
    for (int mt = 0; mt < 2; ++mt)
        #pragma unroll
        for (int r = 0; r < 4; ++r) {
            int node = mt * 16 + fq * 4 + r;
            #pragma unroll
            for (int j = 0; j < 4; ++j) {
                int col = w * 64 + j * 16 + fr;
                float m = acc[mt][j][r] + bias[j];
                out[(size_t)(n0 + node) * 256 + col] = fmaxf(m, 0.f);
                sX[node * SXS + col] = f2b(1.f / (1.f + __expf(-m)));
            }
        }
    __syncthreads();

    // ---------------- gate GEMM: sigmoid(s_m) @ Wgw^T -> sigmoid -> sGate ------
    {
        const int gmt = w & 1, gnt = w >> 1;
        f32x4 g = (f32x4){0.f, 0.f, 0.f, 0.f};
        #pragma unroll
        for (int ks = 0; ks < 8; ++ks) {
            bf16x8 a = *(const bf16x8*)&sX[(gmt * 16 + fr) * SXS + ks * 32 + fq * 8];
            bf16x8 b;
            if (USE_WS) b = *(const bf16x8*)&wpack[73728 + ks * 1024 + (gnt * 16 + fr) * 32 + fq * 8];
            else        b = cvt8(&Wgw[(gnt * 16 + fr) * 256 + ks * 32 + fq * 8]);
            g = __builtin_amdgcn_mfma_f32_16x16x32_bf16(a, b, g, 0, 0, 0);
        }
        int mo = gnt * 16 + fr;
        float gb = Wgb[mo];
        #pragma unroll
        for (int r = 0; r < 4; ++r) {
            int node = gmt * 16 + fq * 4 + r;
            sGate[node * 32 + mo] = 1.f / (1.f + __expf(-(g[r] + gb)));
        }
    }
    __syncthreads();            // gate ready; sX dead -> f32 V_dash scratch

    // ---------------- phase D: V_mu = Wmu@V_h (f32); gate; coalesced store -----
    float* sc = (float*)sX;
    #pragma unroll
    for (int i = 0; i < 4; ++i) {
        int p = i * NT + t;
        int n = p >> 5, m = p & 31;
        const float4* vt4 = (const float4*)&sV[n * 96];
        const float4* wm4 = (const float4*)&Wmu[m * 32];
        float a0 = 0.f, a1 = 0.f, a2 = 0.f;
        #pragma unroll
        for (int v4 = 0; v4 < 8; ++v4) {
            float4 wv = wm4[v4];
            float4 p0 = vt4[v4 * 3 + 0], p1 = vt4[v4 * 3 + 1], p2 = vt4[v4 * 3 + 2];
            a0 = fmaf(wv.x, p0.x, a0); a1 = fmaf(wv.x, p0.y, a1); a2 = fmaf(wv.x, p0.z, a2);
            a0 = fmaf(wv.y, p0.w, a0); a1 = fmaf(wv.y, p1.x, a1); a2 = fmaf(wv.y, p1.y, a2);
            a0 = fmaf(wv.z, p1.z, a0); a1 = fmaf(wv.z, p1.w, a1); a2 = fmaf(wv.z, p2.x, a2);
            a0 = fmaf(wv.w, p2.y, a0); a1 = fmaf(wv.w, p2.z, a1); a2 = fmaf(wv.w, p2.w, a2);
        }
        float g = sGate[n * 32 + m];
        sc[n * 96 + m * 3 + 0] = g * a0;
        sc[n * 96 + m * 3 + 1] = g * a1;
        sc[n * 96 + m * 3 + 2] = g * a2;
    }
    __syncthreads();
    const size_t VBASE = (size_t)NTOT * 256;
    #pragma unroll
    for (int i = 0; i < 3; ++i) {
        int f = i * NT + t;
        *(float4*)&out[VBASE + (size_t)n0 * 96 + f * 4] = *(const float4*)&sc[f * 4];
    }
}

extern "C" void kernel_launch(void* const* d_in, const int* in_sizes, int n_in,
                              void* d_out, int out_size, void* d_ws, size_t ws_size,
                              hipStream_t stream) {
    const float* s   = (const float*)d_in[0];
    const float* V   = (const float*)d_in[1];
    const float* Wh  = (const float*)d_in[2];
    const float* Wmu = (const float*)d_in[3];
    const float* Wmw = (const float*)d_in[4];
    const float* Wmb = (const float*)d_in[5];
    const float* Wgw = (const float*)d_in[6];
    const float* Wgb = (const float*)d_in[7];
    float* out = (float*)d_out;

    dim3 grid(NTOT / BN);   // 8192
    dim3 block(NT);         // 256

    if (ws_size >= 163840) {
        pack_w<<<320, 256, 0, stream>>>(Wmw, Wgw, (unsigned short*)d_ws);
        gvp_main<1><<<grid, block, 0, stream>>>(s, V, Wh, Wmu, Wmw, Wmb, Wgw, Wgb,
                                                (const unsigned short*)d_ws, out);
    } else {
        gvp_main<0><<<grid, block, 0, stream>>>(s, V, Wh, Wmu, Wmw, Wmb, Wgw, Wgb,
                                                nullptr, out);
    }
}